// Round 5
// baseline (326.388 us; speedup 1.0000x reference)
//
#include <hip/hip_runtime.h>
#include <cstdint>
#include <cstddef>

// ---------------------------------------------------------------------------
// GCN+LPA on MI355X.
// R13: R11 structure (best: 307.6us) + ONLY the bin_scan fold from R12.
// R12 bundled {scan fold, gemm64||spmm merge} and regressed +12us: the merge
// ran 12.5k latency-bound spmm blocks at the merged kernel's (gemm-sized)
// VGPR allocation -> occupancy drop, the R10 failure mode. Lesson: gathers
// punish anything that cuts wave concurrency; only pure launch-boundary
// removals win. Scan fold is such a removal (single-block kernel folded into
// count_prep's last block; HW-proven correct in R12's passing run).
// Gather kernels byte-identical to R8. 10 dispatches.
// NOTE: packing assumes N < 65536 (row/col fit 16 bits). N = 50000 here.
// ---------------------------------------------------------------------------

#define WS_ALIGN(x) (((x) + 255) & ~((size_t)255))

typedef __attribute__((ext_vector_type(8))) short short8;
typedef __attribute__((ext_vector_type(4))) float floatx4;

__device__ __forceinline__ unsigned short f2bf(float f) {
    unsigned u = __float_as_uint(f);
    u += 0x7fffu + ((u >> 16) & 1u);          // round-to-nearest-even
    return (unsigned short)(u >> 16);
}
__device__ __forceinline__ float bf_lo(unsigned u) { return __uint_as_float(u << 16); }
__device__ __forceinline__ float bf_hi(unsigned u) { return __uint_as_float(u & 0xffff0000u); }
__device__ __forceinline__ unsigned pack_bf2(float a, float b) {
    return (unsigned)f2bf(a) | ((unsigned)f2bf(b) << 16);
}
__device__ __forceinline__ float sigmoidf(float x) {
    return 1.f / (1.f + __expf(-x));
}
__device__ __forceinline__ int2 ld_nt_int2(const int2* p) {
    long long v = __builtin_nontemporal_load((const long long*)p);
    int2 r;
    r.x = (int)(unsigned)(v & 0xffffffffLL);
    r.y = (int)(v >> 32);
    return r;
}

static const int NBLK = 256;   // blocks for binning passes
#define MAXNB 256              // max coarse buckets supported (N <= 65536)

// ---------------------------------------------------------------------------
// CSR build pieces (2-level counting sort, LDS atomics only)
// ---------------------------------------------------------------------------
__device__ __forceinline__ void binA_count_body(const int* __restrict__ row,
                                                int* __restrict__ bucket_count,
                                                int* __restrict__ bases,
                                                int E, int chunk, int NB, int blk)
{
    __shared__ int hist[MAXNB];
    const int t = threadIdx.x;
    if (t < NB) hist[t] = 0;
    __syncthreads();
    const int s = blk * chunk;
    const int e = min(E, s + chunk);
    for (int i = s + t; i < e; i += 256)
        atomicAdd(&hist[row[i] >> 8], 1);
    __syncthreads();
    if (t < NB)
        bases[blk * NB + t] = atomicAdd(&bucket_count[t], hist[t]);
}

__device__ __forceinline__ void binA_scatter_body(const int* __restrict__ row,
                                                  const int* __restrict__ colv,
                                                  const float* __restrict__ ea,
                                                  const int* __restrict__ bucket_start,
                                                  const int* __restrict__ bases,
                                                  int2* __restrict__ bk,
                                                  int E, int chunk, int NB, int blk)
{
    __shared__ int cur[MAXNB];
    const int t = threadIdx.x;
    if (t < NB) cur[t] = bucket_start[t] + bases[blk * NB + t];
    __syncthreads();
    const int s = blk * chunk;
    const int e = min(E, s + chunk);
    for (int i = s + t; i < e; i += 256) {
        int r = row[i];
        int bin = r >> 8;
        int pos = atomicAdd(&cur[bin], 1);
        bk[pos] = make_int2(((r & 255) << 16) | colv[i], __float_as_int(ea[i]));
    }
}

__launch_bounds__(256)
__global__ void binB(const int2* __restrict__ bk, const int* __restrict__ bucket_start,
                     int* __restrict__ rowptr, int2* __restrict__ edges, int N)
{
    __shared__ int cnt[256];
    __shared__ float deg[256];
    __shared__ float inv[256];
    __shared__ int excl_s[256];
    __shared__ int cur[256];
    __shared__ int scantmp[256];
    const int b = blockIdx.x;
    const int t = threadIdx.x;
    const int s = bucket_start[b];
    const int e = bucket_start[b + 1];
    cnt[t] = 0;
    deg[t] = 0.f;
    __syncthreads();
    for (int i = s + t; i < e; i += 256) {
        int2 v = bk[i];
        int rl = ((unsigned)v.x) >> 16;
        atomicAdd(&cnt[rl], 1);
        atomicAdd(&deg[rl], __int_as_float(v.y));
    }
    __syncthreads();
    const int myc = cnt[t];
    scantmp[t] = myc;
    __syncthreads();
    for (int off = 1; off < 256; off <<= 1) {
        int u = (t >= off) ? scantmp[t - off] : 0;
        __syncthreads();
        scantmp[t] += u;
        __syncthreads();
    }
    const int excl = scantmp[t] - myc;
    excl_s[t] = excl;
    float d = deg[t];
    inv[t] = (d > 0.f) ? 1.f / d : 0.f;
    cur[t] = 0;
    const int gr = b * 256 + t;
    if (gr <= N) rowptr[gr] = s + excl;
    __syncthreads();
    for (int i = s + t; i < e; i += 256) {
        int2 v = bk[i];
        int rl = ((unsigned)v.x) >> 16;
        int c = v.x & 0xffff;
        int p = s + excl_s[rl] + atomicAdd(&cur[rl], 1);
        edges[p] = make_int2(c, __float_as_int(__int_as_float(v.y) * inv[rl]));
    }
}

// ---------------------------------------------------------------------------
// Prep bodies: pack W[128,COLS] f32 -> bf16 MFMA B-fragment order; soft->bf16.
// ---------------------------------------------------------------------------
template<int COLS>
__device__ __forceinline__ void pack_w_body(const float* __restrict__ W,
                                            unsigned short* __restrict__ Wp, int idx)
{
    const int total = (COLS / 16) * 4 * 64;
    if (idx >= total) return;
    const int l = idx & 63;
    const int t = (idx >> 6) & 3;
    const int ct = idx >> 8;
    const int kbase = t * 32 + (l >> 4) * 8;
    const int col = ct * 16 + (l & 15);
    unsigned short v[8];
#pragma unroll
    for (int j = 0; j < 8; ++j)
        v[j] = f2bf(W[(size_t)(kbase + j) * COLS + col]);
    uint4 o;
    o.x = (unsigned)v[0] | ((unsigned)v[1] << 16);
    o.y = (unsigned)v[2] | ((unsigned)v[3] << 16);
    o.z = (unsigned)v[4] | ((unsigned)v[5] << 16);
    o.w = (unsigned)v[6] | ((unsigned)v[7] << 16);
    *(uint4*)(Wp + (size_t)idx * 8) = o;
}

// MERGED: binA_count (blocks [0,NBLK)) || prep (blocks >= NBLK).
// Last counting block performs the bucket prefix scan (removes bin_scan
// launch). Done-counter at bucket_count[MAXNB]; count reads via device-scope
// atomicAdd(p,0) to avoid stale per-XCD L2 copies (plain loads unsafe, G16).
__launch_bounds__(256)
__global__ void count_prep(const int* __restrict__ row, int* __restrict__ bucket_count,
                           int* __restrict__ bases, int* __restrict__ bucket_start,
                           int E, int chunk, int NB,
                           const float* __restrict__ soft, unsigned short* __restrict__ softb,
                           int ns2,
                           const float* __restrict__ w1, unsigned short* __restrict__ w1p,
                           const float* __restrict__ w2, unsigned short* __restrict__ w2p)
{
    const int b = blockIdx.x;
    const int t = threadIdx.x;
    if (b < NBLK) {
        binA_count_body(row, bucket_count, bases, E, chunk, NB, b);
        __threadfence();
        __shared__ int amLast;
        if (t == 0)
            amLast = (atomicAdd(&bucket_count[MAXNB], 1) == NBLK - 1);
        __syncthreads();
        if (amLast) {
            __threadfence();
            __shared__ int s[256];
            int v = (t < NB) ? atomicAdd(&bucket_count[t], 0) : 0;
            s[t] = v;
            __syncthreads();
            for (int off = 1; off < 256; off <<= 1) {
                int u = (t >= off) ? s[t - off] : 0;
                __syncthreads();
                s[t] += u;
                __syncthreads();
            }
            if (t <= NB) bucket_start[t] = s[t] - v;   // t==NB: total == E
        }
    } else {
        const int bb = b - NBLK;
        if (bb < 8) {
            pack_w_body<128>(w1, w1p, bb * 256 + t);
        } else if (bb < 12) {
            pack_w_body<64>(w2, w2p, (bb - 8) * 256 + t);
        } else {
            int i = (bb - 12) * 256 + t;
            if (i < ns2) {
                float2 v = ((const float2*)soft)[i];
                ((unsigned*)softb)[i] = pack_bf2(v.x, v.y);
            }
        }
    }
}

// ---------------------------------------------------------------------------
// MFMA GEMM bodies.
// ---------------------------------------------------------------------------
__device__ __forceinline__ void gemm128_f32a_body(const float* __restrict__ A,
                                                  const unsigned short* __restrict__ Wp,
                                                  unsigned short* __restrict__ C, int M, int bid)
{
    const int COLS = 128;
    const int wave = threadIdx.x >> 6;
    const int lane = threadIdx.x & 63;
    const int row0 = bid * 64 + wave * 16;
    const int m = lane & 15;
    const int q = lane >> 4;

    const int arow = row0 + m;
    const bool avalid = arow < M;
    short8 a[4];
#pragma unroll
    for (int t = 0; t < 4; ++t) {
        if (avalid) {
            float4 f0 = *(const float4*)(A + (size_t)arow * 128 + t * 32 + q * 8);
            float4 f1 = *(const float4*)(A + (size_t)arow * 128 + t * 32 + q * 8 + 4);
            a[t][0] = (short)f2bf(f0.x); a[t][1] = (short)f2bf(f0.y);
            a[t][2] = (short)f2bf(f0.z); a[t][3] = (short)f2bf(f0.w);
            a[t][4] = (short)f2bf(f1.x); a[t][5] = (short)f2bf(f1.y);
            a[t][6] = (short)f2bf(f1.z); a[t][7] = (short)f2bf(f1.w);
        } else {
            a[t] = (short8)0;
        }
    }

#pragma unroll
    for (int ct = 0; ct < COLS / 16; ++ct) {
        floatx4 acc = {0.f, 0.f, 0.f, 0.f};
#pragma unroll
        for (int t = 0; t < 4; ++t) {
            short8 b = *(const short8*)(Wp + (size_t)((ct * 4 + t) * 64 + lane) * 8);
            acc = __builtin_amdgcn_mfma_f32_16x16x32_bf16(a[t], b, acc, 0, 0, 0);
        }
        const int col = ct * 16 + m;
#pragma unroll
        for (int r = 0; r < 4; ++r) {
            int orow = row0 + q * 4 + r;
            if (orow < M)
                C[(size_t)orow * COLS + col] = f2bf(acc[r]);
        }
    }
}

// MERGED: gemm128 (blocks [0,gGemm)) || binA_scatter (blocks >= gGemm).
__launch_bounds__(256)
__global__ void gemm_scatter(const float* __restrict__ A, const unsigned short* __restrict__ Wp,
                             unsigned short* __restrict__ C, int M, int gGemm,
                             const int* __restrict__ row, const int* __restrict__ colv,
                             const float* __restrict__ ea,
                             const int* __restrict__ bucket_start, const int* __restrict__ bases,
                             int2* __restrict__ bk, int E, int chunk, int NB)
{
    const int b = blockIdx.x;
    if (b < gGemm) {
        gemm128_f32a_body(A, Wp, C, M, b);
    } else {
        binA_scatter_body(row, colv, ea, bucket_start, bases, bk, E, chunk, NB, b - gGemm);
    }
}

// MFMA GEMM (bf16 A): standalone, COLS=64 used for logits.
template<int COLS>
__launch_bounds__(256)
__global__ void gemm_mfma(const unsigned short* __restrict__ A,
                          const unsigned short* __restrict__ Wp,
                          unsigned short* __restrict__ C, int M)
{
    const int wave = threadIdx.x >> 6;
    const int lane = threadIdx.x & 63;
    const int row0 = blockIdx.x * 64 + wave * 16;
    const int m = lane & 15;
    const int q = lane >> 4;

    const int arow = row0 + m;
    const bool avalid = arow < M;
    short8 a[4];
#pragma unroll
    for (int t = 0; t < 4; ++t) {
        if (avalid)
            a[t] = *(const short8*)(A + (size_t)arow * 128 + t * 32 + q * 8);
        else
            a[t] = (short8)0;
    }

#pragma unroll
    for (int ct = 0; ct < COLS / 16; ++ct) {
        floatx4 acc = {0.f, 0.f, 0.f, 0.f};
#pragma unroll
        for (int t = 0; t < 4; ++t) {
            short8 b = *(const short8*)(Wp + (size_t)((ct * 4 + t) * 64 + lane) * 8);
            acc = __builtin_amdgcn_mfma_f32_16x16x32_bf16(a[t], b, acc, 0, 0, 0);
        }
        const int col = ct * 16 + m;
#pragma unroll
        for (int r = 0; r < 4; ++r) {
            int orow = row0 + q * 4 + r;
            if (orow < M)
                C[(size_t)orow * COLS + col] = f2bf(acc[r]);
        }
    }
}

// ---------------------------------------------------------------------------
// FUSED 1 (paired-edge, R8-verbatim): F=128 stream (xw1 -> h, bias+relu)
//                                   + F=64 stream (soft -> lab1).
// ---------------------------------------------------------------------------
__launch_bounds__(256)
__global__ void fused1_pair(const int* __restrict__ rowptr, const int2* __restrict__ edges,
                            const uint2* __restrict__ srcA,      // xw1 [N][32] uint2
                            const unsigned* __restrict__ srcB,   // soft [N][32] uint
                            const float* __restrict__ bias,
                            uint2* __restrict__ outA,            // h [N][32] uint2
                            unsigned* __restrict__ outB,         // lab1 [N][32] uint
                            int n)
{
    const int row = blockIdx.x * 4 + (threadIdx.x >> 6);
    const int lane = threadIdx.x & 63;
    const int f = lane & 31;
    const int half = lane >> 5;
    if (row >= n) return;
    const int s = rowptr[row];
    const int e = rowptr[row + 1];

    float a0[4], a1[4], b0[2], b1[2];
#pragma unroll
    for (int j = 0; j < 4; ++j) { a0[j] = 0.f; a1[j] = 0.f; }
    b0[0] = b0[1] = b1[0] = b1[1] = 0.f;

    int i = s;
    for (; i + 8 <= e; i += 8) {                 // 4 paired instrs = 8 edges
        int2 ed[4]; uint2 ua[4]; unsigned ub[4];
#pragma unroll
        for (int j = 0; j < 4; ++j) ed[j] = ld_nt_int2(&edges[i + 2 * j + half]);
#pragma unroll
        for (int j = 0; j < 4; ++j) ua[j] = srcA[(size_t)ed[j].x * 32 + f];
#pragma unroll
        for (int j = 0; j < 4; ++j) ub[j] = srcB[(size_t)ed[j].x * 32 + f];
#pragma unroll
        for (int j = 0; j < 4; ++j) {
            float w = __int_as_float(ed[j].y);
            float* A = (j & 1) ? a1 : a0;
            float* B = (j & 1) ? b1 : b0;
            A[0] = fmaf(w, bf_lo(ua[j].x), A[0]);
            A[1] = fmaf(w, bf_hi(ua[j].x), A[1]);
            A[2] = fmaf(w, bf_lo(ua[j].y), A[2]);
            A[3] = fmaf(w, bf_hi(ua[j].y), A[3]);
            B[0] = fmaf(w, bf_lo(ub[j]), B[0]);
            B[1] = fmaf(w, bf_hi(ub[j]), B[1]);
        }
    }
    for (; i + 2 <= e; i += 2) {                 // paired tail
        int2 ed = ld_nt_int2(&edges[i + half]);
        float w = __int_as_float(ed.y);
        uint2 ua = srcA[(size_t)ed.x * 32 + f];
        unsigned ub = srcB[(size_t)ed.x * 32 + f];
        a0[0] = fmaf(w, bf_lo(ua.x), a0[0]);
        a0[1] = fmaf(w, bf_hi(ua.x), a0[1]);
        a0[2] = fmaf(w, bf_lo(ua.y), a0[2]);
        a0[3] = fmaf(w, bf_hi(ua.y), a0[3]);
        b0[0] = fmaf(w, bf_lo(ub), b0[0]);
        b0[1] = fmaf(w, bf_hi(ub), b0[1]);
    }
    if (i < e && half == 0) {                    // odd leftover: half 0 only
        int2 ed = ld_nt_int2(&edges[i]);
        float w = __int_as_float(ed.y);
        uint2 ua = srcA[(size_t)ed.x * 32 + f];
        unsigned ub = srcB[(size_t)ed.x * 32 + f];
        a1[0] = fmaf(w, bf_lo(ua.x), a1[0]);
        a1[1] = fmaf(w, bf_hi(ua.x), a1[1]);
        a1[2] = fmaf(w, bf_lo(ua.y), a1[2]);
        a1[3] = fmaf(w, bf_hi(ua.y), a1[3]);
        b1[0] = fmaf(w, bf_lo(ub), b1[0]);
        b1[1] = fmaf(w, bf_hi(ub), b1[1]);
    }
    float A0 = a0[0] + a1[0], A1 = a0[1] + a1[1];
    float A2 = a0[2] + a1[2], A3 = a0[3] + a1[3];
    float B0 = b0[0] + b1[0], B1 = b0[1] + b1[1];
    A0 += __shfl_down(A0, 32); A1 += __shfl_down(A1, 32);
    A2 += __shfl_down(A2, 32); A3 += __shfl_down(A3, 32);
    B0 += __shfl_down(B0, 32); B1 += __shfl_down(B1, 32);
    if (half == 0) {
        float4 bb = *(const float4*)(bias + 4 * f);
        A0 = fmaxf(A0 + bb.x, 0.f);
        A1 = fmaxf(A1 + bb.y, 0.f);
        A2 = fmaxf(A2 + bb.z, 0.f);
        A3 = fmaxf(A3 + bb.w, 0.f);
        uint2 o;
        o.x = pack_bf2(A0, A1);
        o.y = pack_bf2(A2, A3);
        outA[(size_t)row * 32 + f] = o;
        outB[(size_t)row * 32 + f] = pack_bf2(B0, B1);
    }
}

// ---------------------------------------------------------------------------
// FUSED 2 (paired-edge, R8-verbatim): A: logits -> out0 (bias+sigmoid, f32).
//                                     B: lab1 -> lab2 (bf16 packed).
// ---------------------------------------------------------------------------
__launch_bounds__(256)
__global__ void fused2_pair(const int* __restrict__ rowptr, const int2* __restrict__ edges,
                            const unsigned* __restrict__ srcA,   // logits [N][32] uint
                            const unsigned* __restrict__ srcB,   // lab1 [N][32] uint
                            const float* __restrict__ bias,
                            float* __restrict__ outA,            // out0 f32 [N][64]
                            unsigned* __restrict__ outB,         // lab2 [N][32] uint
                            int n)
{
    const int row = blockIdx.x * 4 + (threadIdx.x >> 6);
    const int lane = threadIdx.x & 63;
    const int f = lane & 31;
    const int half = lane >> 5;
    if (row >= n) return;
    const int s = rowptr[row];
    const int e = rowptr[row + 1];

    float a0[2], a1[2], b0[2], b1[2];
    a0[0] = a0[1] = a1[0] = a1[1] = 0.f;
    b0[0] = b0[1] = b1[0] = b1[1] = 0.f;

    int i = s;
    for (; i + 8 <= e; i += 8) {
        int2 ed[4]; unsigned ua[4], ub[4];
#pragma unroll
        for (int j = 0; j < 4; ++j) ed[j] = ld_nt_int2(&edges[i + 2 * j + half]);
#pragma unroll
        for (int j = 0; j < 4; ++j) ua[j] = srcA[(size_t)ed[j].x * 32 + f];
#pragma unroll
        for (int j = 0; j < 4; ++j) ub[j] = srcB[(size_t)ed[j].x * 32 + f];
#pragma unroll
        for (int j = 0; j < 4; ++j) {
            float w = __int_as_float(ed[j].y);
            float* A = (j & 1) ? a1 : a0;
            float* B = (j & 1) ? b1 : b0;
            A[0] = fmaf(w, bf_lo(ua[j]), A[0]);
            A[1] = fmaf(w, bf_hi(ua[j]), A[1]);
            B[0] = fmaf(w, bf_lo(ub[j]), B[0]);
            B[1] = fmaf(w, bf_hi(ub[j]), B[1]);
        }
    }
    for (; i + 2 <= e; i += 2) {
        int2 ed = ld_nt_int2(&edges[i + half]);
        float w = __int_as_float(ed.y);
        unsigned ua = srcA[(size_t)ed.x * 32 + f];
        unsigned ub = srcB[(size_t)ed.x * 32 + f];
        a0[0] = fmaf(w, bf_lo(ua), a0[0]);
        a0[1] = fmaf(w, bf_hi(ua), a0[1]);
        b0[0] = fmaf(w, bf_lo(ub), b0[0]);
        b0[1] = fmaf(w, bf_hi(ub), b0[1]);
    }
    if (i < e && half == 0) {
        int2 ed = ld_nt_int2(&edges[i]);
        float w = __int_as_float(ed.y);
        unsigned ua = srcA[(size_t)ed.x * 32 + f];
        unsigned ub = srcB[(size_t)ed.x * 32 + f];
        a1[0] = fmaf(w, bf_lo(ua), a1[0]);
        a1[1] = fmaf(w, bf_hi(ua), a1[1]);
        b1[0] = fmaf(w, bf_lo(ub), b1[0]);
        b1[1] = fmaf(w, bf_hi(ub), b1[1]);
    }
    float A0 = a0[0] + a1[0], A1 = a0[1] + a1[1];
    float B0 = b0[0] + b1[0], B1 = b0[1] + b1[1];
    A0 += __shfl_down(A0, 32); A1 += __shfl_down(A1, 32);
    B0 += __shfl_down(B0, 32); B1 += __shfl_down(B1, 32);
    if (half == 0) {
        float2 bb = *(const float2*)(bias + 2 * f);
        float2 o;
        o.x = sigmoidf(A0 + bb.x);
        o.y = sigmoidf(A1 + bb.y);
        *(float2*)(outA + (size_t)row * 64 + 2 * f) = o;
        outB[(size_t)row * 32 + f] = pack_bf2(B0, B1);
    }
}

// ---------------------------------------------------------------------------
// Solo SpMM F=64 (paired-edge, R8-verbatim). ACT: 0 none (bf16), 3 sigmoid.
// ---------------------------------------------------------------------------
template<int ACT>
__launch_bounds__(256)
__global__ void spmm64_pair(const int* __restrict__ rowptr, const int2* __restrict__ edges,
                            const unsigned* __restrict__ src,    // [N][32] uint
                            void* __restrict__ out, int n)
{
    const int row = blockIdx.x * 4 + (threadIdx.x >> 6);
    const int lane = threadIdx.x & 63;
    const int f = lane & 31;
    const int half = lane >> 5;
    if (row >= n) return;
    const int s = rowptr[row];
    const int e = rowptr[row + 1];

    float a[4][2];
#pragma unroll
    for (int j = 0; j < 4; ++j) { a[j][0] = 0.f; a[j][1] = 0.f; }

    int i = s;
    for (; i + 8 <= e; i += 8) {
        int2 ed[4]; unsigned u[4];
#pragma unroll
        for (int j = 0; j < 4; ++j) ed[j] = ld_nt_int2(&edges[i + 2 * j + half]);
#pragma unroll
        for (int j = 0; j < 4; ++j) u[j] = src[(size_t)ed[j].x * 32 + f];
#pragma unroll
        for (int j = 0; j < 4; ++j) {
            float w = __int_as_float(ed[j].y);
            a[j][0] = fmaf(w, bf_lo(u[j]), a[j][0]);
            a[j][1] = fmaf(w, bf_hi(u[j]), a[j][1]);
        }
    }
    for (; i + 2 <= e; i += 2) {
        int2 ed = ld_nt_int2(&edges[i + half]);
        float w = __int_as_float(ed.y);
        unsigned u = src[(size_t)ed.x * 32 + f];
        a[0][0] = fmaf(w, bf_lo(u), a[0][0]);
        a[0][1] = fmaf(w, bf_hi(u), a[0][1]);
    }
    if (i < e && half == 0) {
        int2 ed = ld_nt_int2(&edges[i]);
        float w = __int_as_float(ed.y);
        unsigned u = src[(size_t)ed.x * 32 + f];
        a[1][0] = fmaf(w, bf_lo(u), a[1][0]);
        a[1][1] = fmaf(w, bf_hi(u), a[1][1]);
    }
    float v0 = (a[0][0] + a[1][0]) + (a[2][0] + a[3][0]);
    float v1 = (a[0][1] + a[1][1]) + (a[2][1] + a[3][1]);
    v0 += __shfl_down(v0, 32);
    v1 += __shfl_down(v1, 32);
    if (half == 0) {
        if (ACT == 0) {
            ((unsigned*)out)[(size_t)row * 32 + f] = pack_bf2(v0, v1);
        } else {
            float2 o;
            o.x = sigmoidf(v0);
            o.y = sigmoidf(v1);
            *(float2*)((float*)out + (size_t)row * 64 + 2 * f) = o;
        }
    }
}

// ---------------------------------------------------------------------------
extern "C" void kernel_launch(void* const* d_in, const int* in_sizes, int n_in,
                              void* d_out, int out_size, void* d_ws, size_t ws_size,
                              hipStream_t stream)
{
    const float* x    = (const float*)d_in[0];
    const float* soft = (const float*)d_in[1];
    const float* ea   = (const float*)d_in[2];
    const float* w1   = (const float*)d_in[3];
    const float* b1   = (const float*)d_in[4];
    const float* w2   = (const float*)d_in[5];
    const float* b2   = (const float*)d_in[6];
    const int*   eidx = (const int*)d_in[7];

    const int N = in_sizes[0] / 128;
    const int E = in_sizes[2];
    const int* row  = eidx;
    const int* colv = eidx + E;
    const int NB = (N + 255) / 256;            // coarse buckets (<= 256)
    const int chunk = (E + NBLK - 1) / NBLK;

    uint8_t* ws = (uint8_t*)d_ws;
    size_t off = 0;
    auto alloc = [&](size_t bytes) -> void* {
        void* p = ws + off;
        off += WS_ALIGN(bytes);
        return p;
    };
    int*  bucket_count = (int*) alloc(((size_t)MAXNB + 1) * 4);   // +1: done counter
    int*  bucket_start = (int*) alloc(((size_t)NB + 1) * 4);
    int*  bases        = (int*) alloc((size_t)NBLK * NB * 4);
    int*  rowptr       = (int*) alloc(((size_t)N + 1) * 4);
    int2* bk           = (int2*)alloc((size_t)E * 8);
    int2* edges        = (int2*)alloc((size_t)E * 8 + 64);
    unsigned short* w1p     = (unsigned short*)alloc((size_t)128 * 128 * 2);
    unsigned short* w2p     = (unsigned short*)alloc((size_t)128 * 64 * 2);
    unsigned short* xw1b    = (unsigned short*)alloc((size_t)N * 128 * 2);
    unsigned short* hb      = (unsigned short*)alloc((size_t)N * 128 * 2);
    unsigned short* logitsb = (unsigned short*)alloc((size_t)N * 64 * 2);
    unsigned short* softb   = (unsigned short*)alloc((size_t)N * 64 * 2);
    unsigned short* labA    = (unsigned short*)alloc((size_t)N * 64 * 2);
    unsigned short* labB    = (unsigned short*)alloc((size_t)N * 64 * 2);

    float* out0 = (float*)d_out;             // x_out [N,64]
    float* out1 = out0 + (size_t)N * 64;     // labels [N,64]

    hipMemsetAsync(bucket_count, 0, ((size_t)MAXNB + 1) * 4, stream);

    const int ns2 = (N * 64) / 2;
    const int gGemm = (N + 63) / 64;
    const int gSp   = (N + 3) / 4;

    // MERGED: binA_count (+last-block scan) || prep (w-pack, soft->bf16).
    const int gCP = NBLK + 12 + (ns2 + 255) / 256;
    count_prep<<<gCP, 256, 0, stream>>>(row, bucket_count, bases, bucket_start,
                                        E, chunk, NB, soft, softb, ns2, w1, w1p, w2, w2p);

    // MERGED: gemm128 (xw1, independent of CSR) || binA_scatter.
    gemm_scatter<<<gGemm + NBLK, 256, 0, stream>>>(x, w1p, xw1b, N, gGemm,
                                                   row, colv, ea, bucket_start, bases,
                                                   bk, E, chunk, NB);

    binB<<<NB, 256, 0, stream>>>(bk, bucket_start, rowptr, edges, N);

    // fused pass 1: h = relu(spmm(xw1)+b1), lab1 = spmm(soft)
    fused1_pair<<<gSp, 256, 0, stream>>>(rowptr, edges, (const uint2*)xw1b,
                                         (const unsigned*)softb, b1,
                                         (uint2*)hb, (unsigned*)labA, N);

    gemm_mfma<64><<<gGemm, 256, 0, stream>>>(hb, w2p, logitsb, N);       // logits (bf16)

    // fused pass 2: out0 = sigmoid(spmm(logits)+b2), lab2 = spmm(lab1)
    fused2_pair<<<gSp, 256, 0, stream>>>(rowptr, edges, (const unsigned*)logitsb,
                                         (const unsigned*)labA, b2,
                                         out0, (unsigned*)labB, N);

    // LPA tail (dependent): lab3, lab4, out1
    spmm64_pair<0><<<gSp, 256, 0, stream>>>(rowptr, edges, (const unsigned*)labB, labA, N);
    spmm64_pair<0><<<gSp, 256, 0, stream>>>(rowptr, edges, (const unsigned*)labA, labB, N);
    spmm64_pair<3><<<gSp, 256, 0, stream>>>(rowptr, edges, (const unsigned*)labB, out1, N);
}

// Round 7
// 306.166 us; speedup vs baseline: 1.0660x; 1.0660x over previous
//
#include <hip/hip_runtime.h>
#include <cstdint>
#include <cstddef>

// ---------------------------------------------------------------------------
// GCN+LPA on MI355X.
// R15: resubmit of R14 (verbatim R11 structure, session best 307.6us) after
// an infra-only bench failure (container failed twice; no kernel signal).
// R13 isolated the bin_scan fold as a regression (+12-19us): an in-kernel
// device-scope barrier (threadfence + done-counter) costs more than the
// 1-block launch it replaces. Axis inventory complete: bytes (R7), addresses
// (R9), per-wave MLP (R10), occupancy coupling (R10/R12), launch merges
// (R11 win only when per-block resources untouched). Gathers pinned at
// ~3.3 TB/s effective = random-gather L2-miss-concurrency ceiling.
// Structure: count||prep merge, bin_scan solo, gemm128||scatter merge, binB,
// fused1, gemm64, fused2, spmm x3. Gather kernels byte-identical to R8.
// NOTE: packing assumes N < 65536 (row/col fit 16 bits). N = 50000 here.
// ---------------------------------------------------------------------------

#define WS_ALIGN(x) (((x) + 255) & ~((size_t)255))

typedef __attribute__((ext_vector_type(8))) short short8;
typedef __attribute__((ext_vector_type(4))) float floatx4;

__device__ __forceinline__ unsigned short f2bf(float f) {
    unsigned u = __float_as_uint(f);
    u += 0x7fffu + ((u >> 16) & 1u);          // round-to-nearest-even
    return (unsigned short)(u >> 16);
}
__device__ __forceinline__ float bf_lo(unsigned u) { return __uint_as_float(u << 16); }
__device__ __forceinline__ float bf_hi(unsigned u) { return __uint_as_float(u & 0xffff0000u); }
__device__ __forceinline__ unsigned pack_bf2(float a, float b) {
    return (unsigned)f2bf(a) | ((unsigned)f2bf(b) << 16);
}
__device__ __forceinline__ float sigmoidf(float x) {
    return 1.f / (1.f + __expf(-x));
}
__device__ __forceinline__ int2 ld_nt_int2(const int2* p) {
    long long v = __builtin_nontemporal_load((const long long*)p);
    int2 r;
    r.x = (int)(unsigned)(v & 0xffffffffLL);
    r.y = (int)(v >> 32);
    return r;
}

static const int NBLK = 256;   // blocks for binning passes
#define MAXNB 256              // max coarse buckets supported (N <= 65536)

// ---------------------------------------------------------------------------
// CSR build pieces (2-level counting sort, LDS atomics only)
// ---------------------------------------------------------------------------
__device__ __forceinline__ void binA_count_body(const int* __restrict__ row,
                                                int* __restrict__ bucket_count,
                                                int* __restrict__ bases,
                                                int E, int chunk, int NB, int blk)
{
    __shared__ int hist[MAXNB];
    const int t = threadIdx.x;
    if (t < NB) hist[t] = 0;
    __syncthreads();
    const int s = blk * chunk;
    const int e = min(E, s + chunk);
    for (int i = s + t; i < e; i += 256)
        atomicAdd(&hist[row[i] >> 8], 1);
    __syncthreads();
    if (t < NB)
        bases[blk * NB + t] = atomicAdd(&bucket_count[t], hist[t]);
}

__launch_bounds__(256)
__global__ void bin_scan(const int* __restrict__ bucket_count, int* __restrict__ bucket_start,
                         int NB)
{
    __shared__ int s[256];
    const int t = threadIdx.x;
    int v = (t < NB) ? bucket_count[t] : 0;
    s[t] = v;
    __syncthreads();
    for (int off = 1; off < 256; off <<= 1) {
        int u = (t >= off) ? s[t - off] : 0;
        __syncthreads();
        s[t] += u;
        __syncthreads();
    }
    int excl = s[t] - v;
    if (t <= NB) bucket_start[t] = excl;   // t==NB: total == E
}

__device__ __forceinline__ void binA_scatter_body(const int* __restrict__ row,
                                                  const int* __restrict__ colv,
                                                  const float* __restrict__ ea,
                                                  const int* __restrict__ bucket_start,
                                                  const int* __restrict__ bases,
                                                  int2* __restrict__ bk,
                                                  int E, int chunk, int NB, int blk)
{
    __shared__ int cur[MAXNB];
    const int t = threadIdx.x;
    if (t < NB) cur[t] = bucket_start[t] + bases[blk * NB + t];
    __syncthreads();
    const int s = blk * chunk;
    const int e = min(E, s + chunk);
    for (int i = s + t; i < e; i += 256) {
        int r = row[i];
        int bin = r >> 8;
        int pos = atomicAdd(&cur[bin], 1);
        bk[pos] = make_int2(((r & 255) << 16) | colv[i], __float_as_int(ea[i]));
    }
}

__launch_bounds__(256)
__global__ void binB(const int2* __restrict__ bk, const int* __restrict__ bucket_start,
                     int* __restrict__ rowptr, int2* __restrict__ edges, int N)
{
    __shared__ int cnt[256];
    __shared__ float deg[256];
    __shared__ float inv[256];
    __shared__ int excl_s[256];
    __shared__ int cur[256];
    __shared__ int scantmp[256];
    const int b = blockIdx.x;
    const int t = threadIdx.x;
    const int s = bucket_start[b];
    const int e = bucket_start[b + 1];
    cnt[t] = 0;
    deg[t] = 0.f;
    __syncthreads();
    for (int i = s + t; i < e; i += 256) {
        int2 v = bk[i];
        int rl = ((unsigned)v.x) >> 16;
        atomicAdd(&cnt[rl], 1);
        atomicAdd(&deg[rl], __int_as_float(v.y));
    }
    __syncthreads();
    const int myc = cnt[t];
    scantmp[t] = myc;
    __syncthreads();
    for (int off = 1; off < 256; off <<= 1) {
        int u = (t >= off) ? scantmp[t - off] : 0;
        __syncthreads();
        scantmp[t] += u;
        __syncthreads();
    }
    const int excl = scantmp[t] - myc;
    excl_s[t] = excl;
    float d = deg[t];
    inv[t] = (d > 0.f) ? 1.f / d : 0.f;
    cur[t] = 0;
    const int gr = b * 256 + t;
    if (gr <= N) rowptr[gr] = s + excl;
    __syncthreads();
    for (int i = s + t; i < e; i += 256) {
        int2 v = bk[i];
        int rl = ((unsigned)v.x) >> 16;
        int c = v.x & 0xffff;
        int p = s + excl_s[rl] + atomicAdd(&cur[rl], 1);
        edges[p] = make_int2(c, __float_as_int(__int_as_float(v.y) * inv[rl]));
    }
}

// ---------------------------------------------------------------------------
// Prep bodies: pack W[128,COLS] f32 -> bf16 MFMA B-fragment order; soft->bf16.
// ---------------------------------------------------------------------------
template<int COLS>
__device__ __forceinline__ void pack_w_body(const float* __restrict__ W,
                                            unsigned short* __restrict__ Wp, int idx)
{
    const int total = (COLS / 16) * 4 * 64;
    if (idx >= total) return;
    const int l = idx & 63;
    const int t = (idx >> 6) & 3;
    const int ct = idx >> 8;
    const int kbase = t * 32 + (l >> 4) * 8;
    const int col = ct * 16 + (l & 15);
    unsigned short v[8];
#pragma unroll
    for (int j = 0; j < 8; ++j)
        v[j] = f2bf(W[(size_t)(kbase + j) * COLS + col]);
    uint4 o;
    o.x = (unsigned)v[0] | ((unsigned)v[1] << 16);
    o.y = (unsigned)v[2] | ((unsigned)v[3] << 16);
    o.z = (unsigned)v[4] | ((unsigned)v[5] << 16);
    o.w = (unsigned)v[6] | ((unsigned)v[7] << 16);
    *(uint4*)(Wp + (size_t)idx * 8) = o;
}

// MERGED: binA_count (blocks [0,NBLK)) || prep (blocks >= NBLK).
__launch_bounds__(256)
__global__ void count_prep(const int* __restrict__ row, int* __restrict__ bucket_count,
                           int* __restrict__ bases, int E, int chunk, int NB,
                           const float* __restrict__ soft, unsigned short* __restrict__ softb,
                           int ns2,
                           const float* __restrict__ w1, unsigned short* __restrict__ w1p,
                           const float* __restrict__ w2, unsigned short* __restrict__ w2p)
{
    const int b = blockIdx.x;
    const int t = threadIdx.x;
    if (b < NBLK) {
        binA_count_body(row, bucket_count, bases, E, chunk, NB, b);
    } else {
        const int bb = b - NBLK;
        if (bb < 8) {
            pack_w_body<128>(w1, w1p, bb * 256 + t);
        } else if (bb < 12) {
            pack_w_body<64>(w2, w2p, (bb - 8) * 256 + t);
        } else {
            int i = (bb - 12) * 256 + t;
            if (i < ns2) {
                float2 v = ((const float2*)soft)[i];
                ((unsigned*)softb)[i] = pack_bf2(v.x, v.y);
            }
        }
    }
}

// ---------------------------------------------------------------------------
// MFMA GEMM bodies.
// ---------------------------------------------------------------------------
__device__ __forceinline__ void gemm128_f32a_body(const float* __restrict__ A,
                                                  const unsigned short* __restrict__ Wp,
                                                  unsigned short* __restrict__ C, int M, int bid)
{
    const int COLS = 128;
    const int wave = threadIdx.x >> 6;
    const int lane = threadIdx.x & 63;
    const int row0 = bid * 64 + wave * 16;
    const int m = lane & 15;
    const int q = lane >> 4;

    const int arow = row0 + m;
    const bool avalid = arow < M;
    short8 a[4];
#pragma unroll
    for (int t = 0; t < 4; ++t) {
        if (avalid) {
            float4 f0 = *(const float4*)(A + (size_t)arow * 128 + t * 32 + q * 8);
            float4 f1 = *(const float4*)(A + (size_t)arow * 128 + t * 32 + q * 8 + 4);
            a[t][0] = (short)f2bf(f0.x); a[t][1] = (short)f2bf(f0.y);
            a[t][2] = (short)f2bf(f0.z); a[t][3] = (short)f2bf(f0.w);
            a[t][4] = (short)f2bf(f1.x); a[t][5] = (short)f2bf(f1.y);
            a[t][6] = (short)f2bf(f1.z); a[t][7] = (short)f2bf(f1.w);
        } else {
            a[t] = (short8)0;
        }
    }

#pragma unroll
    for (int ct = 0; ct < COLS / 16; ++ct) {
        floatx4 acc = {0.f, 0.f, 0.f, 0.f};
#pragma unroll
        for (int t = 0; t < 4; ++t) {
            short8 b = *(const short8*)(Wp + (size_t)((ct * 4 + t) * 64 + lane) * 8);
            acc = __builtin_amdgcn_mfma_f32_16x16x32_bf16(a[t], b, acc, 0, 0, 0);
        }
        const int col = ct * 16 + m;
#pragma unroll
        for (int r = 0; r < 4; ++r) {
            int orow = row0 + q * 4 + r;
            if (orow < M)
                C[(size_t)orow * COLS + col] = f2bf(acc[r]);
        }
    }
}

// MERGED: gemm128 (blocks [0,gGemm)) || binA_scatter (blocks >= gGemm).
__launch_bounds__(256)
__global__ void gemm_scatter(const float* __restrict__ A, const unsigned short* __restrict__ Wp,
                             unsigned short* __restrict__ C, int M, int gGemm,
                             const int* __restrict__ row, const int* __restrict__ colv,
                             const float* __restrict__ ea,
                             const int* __restrict__ bucket_start, const int* __restrict__ bases,
                             int2* __restrict__ bk, int E, int chunk, int NB)
{
    const int b = blockIdx.x;
    if (b < gGemm) {
        gemm128_f32a_body(A, Wp, C, M, b);
    } else {
        binA_scatter_body(row, colv, ea, bucket_start, bases, bk, E, chunk, NB, b - gGemm);
    }
}

// MFMA GEMM (bf16 A): standalone, COLS=64 used for logits.
template<int COLS>
__launch_bounds__(256)
__global__ void gemm_mfma(const unsigned short* __restrict__ A,
                          const unsigned short* __restrict__ Wp,
                          unsigned short* __restrict__ C, int M)
{
    const int wave = threadIdx.x >> 6;
    const int lane = threadIdx.x & 63;
    const int row0 = blockIdx.x * 64 + wave * 16;
    const int m = lane & 15;
    const int q = lane >> 4;

    const int arow = row0 + m;
    const bool avalid = arow < M;
    short8 a[4];
#pragma unroll
    for (int t = 0; t < 4; ++t) {
        if (avalid)
            a[t] = *(const short8*)(A + (size_t)arow * 128 + t * 32 + q * 8);
        else
            a[t] = (short8)0;
    }

#pragma unroll
    for (int ct = 0; ct < COLS / 16; ++ct) {
        floatx4 acc = {0.f, 0.f, 0.f, 0.f};
#pragma unroll
        for (int t = 0; t < 4; ++t) {
            short8 b = *(const short8*)(Wp + (size_t)((ct * 4 + t) * 64 + lane) * 8);
            acc = __builtin_amdgcn_mfma_f32_16x16x32_bf16(a[t], b, acc, 0, 0, 0);
        }
        const int col = ct * 16 + m;
#pragma unroll
        for (int r = 0; r < 4; ++r) {
            int orow = row0 + q * 4 + r;
            if (orow < M)
                C[(size_t)orow * COLS + col] = f2bf(acc[r]);
        }
    }
}

// ---------------------------------------------------------------------------
// FUSED 1 (paired-edge, R8-verbatim): F=128 stream (xw1 -> h, bias+relu)
//                                   + F=64 stream (soft -> lab1).
// Wave = 1 row; lanes 0-31 handle even edge, 32-63 odd edge; lane covers
// 4 feats (uint2) of xw1 and 2 feats (uint) of soft. Fold via shfl_down(32).
// ---------------------------------------------------------------------------
__launch_bounds__(256)
__global__ void fused1_pair(const int* __restrict__ rowptr, const int2* __restrict__ edges,
                            const uint2* __restrict__ srcA,      // xw1 [N][32] uint2
                            const unsigned* __restrict__ srcB,   // soft [N][32] uint
                            const float* __restrict__ bias,
                            uint2* __restrict__ outA,            // h [N][32] uint2
                            unsigned* __restrict__ outB,         // lab1 [N][32] uint
                            int n)
{
    const int row = blockIdx.x * 4 + (threadIdx.x >> 6);
    const int lane = threadIdx.x & 63;
    const int f = lane & 31;
    const int half = lane >> 5;
    if (row >= n) return;
    const int s = rowptr[row];
    const int e = rowptr[row + 1];

    float a0[4], a1[4], b0[2], b1[2];
#pragma unroll
    for (int j = 0; j < 4; ++j) { a0[j] = 0.f; a1[j] = 0.f; }
    b0[0] = b0[1] = b1[0] = b1[1] = 0.f;

    int i = s;
    for (; i + 8 <= e; i += 8) {                 // 4 paired instrs = 8 edges
        int2 ed[4]; uint2 ua[4]; unsigned ub[4];
#pragma unroll
        for (int j = 0; j < 4; ++j) ed[j] = ld_nt_int2(&edges[i + 2 * j + half]);
#pragma unroll
        for (int j = 0; j < 4; ++j) ua[j] = srcA[(size_t)ed[j].x * 32 + f];
#pragma unroll
        for (int j = 0; j < 4; ++j) ub[j] = srcB[(size_t)ed[j].x * 32 + f];
#pragma unroll
        for (int j = 0; j < 4; ++j) {
            float w = __int_as_float(ed[j].y);
            float* A = (j & 1) ? a1 : a0;
            float* B = (j & 1) ? b1 : b0;
            A[0] = fmaf(w, bf_lo(ua[j].x), A[0]);
            A[1] = fmaf(w, bf_hi(ua[j].x), A[1]);
            A[2] = fmaf(w, bf_lo(ua[j].y), A[2]);
            A[3] = fmaf(w, bf_hi(ua[j].y), A[3]);
            B[0] = fmaf(w, bf_lo(ub[j]), B[0]);
            B[1] = fmaf(w, bf_hi(ub[j]), B[1]);
        }
    }
    for (; i + 2 <= e; i += 2) {                 // paired tail
        int2 ed = ld_nt_int2(&edges[i + half]);
        float w = __int_as_float(ed.y);
        uint2 ua = srcA[(size_t)ed.x * 32 + f];
        unsigned ub = srcB[(size_t)ed.x * 32 + f];
        a0[0] = fmaf(w, bf_lo(ua.x), a0[0]);
        a0[1] = fmaf(w, bf_hi(ua.x), a0[1]);
        a0[2] = fmaf(w, bf_lo(ua.y), a0[2]);
        a0[3] = fmaf(w, bf_hi(ua.y), a0[3]);
        b0[0] = fmaf(w, bf_lo(ub), b0[0]);
        b0[1] = fmaf(w, bf_hi(ub), b0[1]);
    }
    if (i < e && half == 0) {                    // odd leftover: half 0 only
        int2 ed = ld_nt_int2(&edges[i]);
        float w = __int_as_float(ed.y);
        uint2 ua = srcA[(size_t)ed.x * 32 + f];
        unsigned ub = srcB[(size_t)ed.x * 32 + f];
        a1[0] = fmaf(w, bf_lo(ua.x), a1[0]);
        a1[1] = fmaf(w, bf_hi(ua.x), a1[1]);
        a1[2] = fmaf(w, bf_lo(ua.y), a1[2]);
        a1[3] = fmaf(w, bf_hi(ua.y), a1[3]);
        b1[0] = fmaf(w, bf_lo(ub), b1[0]);
        b1[1] = fmaf(w, bf_hi(ub), b1[1]);
    }
    float A0 = a0[0] + a1[0], A1 = a0[1] + a1[1];
    float A2 = a0[2] + a1[2], A3 = a0[3] + a1[3];
    float B0 = b0[0] + b1[0], B1 = b0[1] + b1[1];
    A0 += __shfl_down(A0, 32); A1 += __shfl_down(A1, 32);
    A2 += __shfl_down(A2, 32); A3 += __shfl_down(A3, 32);
    B0 += __shfl_down(B0, 32); B1 += __shfl_down(B1, 32);
    if (half == 0) {
        float4 bb = *(const float4*)(bias + 4 * f);
        A0 = fmaxf(A0 + bb.x, 0.f);
        A1 = fmaxf(A1 + bb.y, 0.f);
        A2 = fmaxf(A2 + bb.z, 0.f);
        A3 = fmaxf(A3 + bb.w, 0.f);
        uint2 o;
        o.x = pack_bf2(A0, A1);
        o.y = pack_bf2(A2, A3);
        outA[(size_t)row * 32 + f] = o;
        outB[(size_t)row * 32 + f] = pack_bf2(B0, B1);
    }
}

// ---------------------------------------------------------------------------
// FUSED 2 (paired-edge, R8-verbatim): A: logits -> out0 (bias+sigmoid, f32).
//                                     B: lab1 -> lab2 (bf16 packed).
// ---------------------------------------------------------------------------
__launch_bounds__(256)
__global__ void fused2_pair(const int* __restrict__ rowptr, const int2* __restrict__ edges,
                            const unsigned* __restrict__ srcA,   // logits [N][32] uint
                            const unsigned* __restrict__ srcB,   // lab1 [N][32] uint
                            const float* __restrict__ bias,
                            float* __restrict__ outA,            // out0 f32 [N][64]
                            unsigned* __restrict__ outB,         // lab2 [N][32] uint
                            int n)
{
    const int row = blockIdx.x * 4 + (threadIdx.x >> 6);
    const int lane = threadIdx.x & 63;
    const int f = lane & 31;
    const int half = lane >> 5;
    if (row >= n) return;
    const int s = rowptr[row];
    const int e = rowptr[row + 1];

    float a0[2], a1[2], b0[2], b1[2];
    a0[0] = a0[1] = a1[0] = a1[1] = 0.f;
    b0[0] = b0[1] = b1[0] = b1[1] = 0.f;

    int i = s;
    for (; i + 8 <= e; i += 8) {
        int2 ed[4]; unsigned ua[4], ub[4];
#pragma unroll
        for (int j = 0; j < 4; ++j) ed[j] = ld_nt_int2(&edges[i + 2 * j + half]);
#pragma unroll
        for (int j = 0; j < 4; ++j) ua[j] = srcA[(size_t)ed[j].x * 32 + f];
#pragma unroll
        for (int j = 0; j < 4; ++j) ub[j] = srcB[(size_t)ed[j].x * 32 + f];
#pragma unroll
        for (int j = 0; j < 4; ++j) {
            float w = __int_as_float(ed[j].y);
            float* A = (j & 1) ? a1 : a0;
            float* B = (j & 1) ? b1 : b0;
            A[0] = fmaf(w, bf_lo(ua[j]), A[0]);
            A[1] = fmaf(w, bf_hi(ua[j]), A[1]);
            B[0] = fmaf(w, bf_lo(ub[j]), B[0]);
            B[1] = fmaf(w, bf_hi(ub[j]), B[1]);
        }
    }
    for (; i + 2 <= e; i += 2) {
        int2 ed = ld_nt_int2(&edges[i + half]);
        float w = __int_as_float(ed.y);
        unsigned ua = srcA[(size_t)ed.x * 32 + f];
        unsigned ub = srcB[(size_t)ed.x * 32 + f];
        a0[0] = fmaf(w, bf_lo(ua), a0[0]);
        a0[1] = fmaf(w, bf_hi(ua), a0[1]);
        b0[0] = fmaf(w, bf_lo(ub), b0[0]);
        b0[1] = fmaf(w, bf_hi(ub), b0[1]);
    }
    if (i < e && half == 0) {
        int2 ed = ld_nt_int2(&edges[i]);
        float w = __int_as_float(ed.y);
        unsigned ua = srcA[(size_t)ed.x * 32 + f];
        unsigned ub = srcB[(size_t)ed.x * 32 + f];
        a1[0] = fmaf(w, bf_lo(ua), a1[0]);
        a1[1] = fmaf(w, bf_hi(ua), a1[1]);
        b1[0] = fmaf(w, bf_lo(ub), b1[0]);
        b1[1] = fmaf(w, bf_hi(ub), b1[1]);
    }
    float A0 = a0[0] + a1[0], A1 = a0[1] + a1[1];
    float B0 = b0[0] + b1[0], B1 = b0[1] + b1[1];
    A0 += __shfl_down(A0, 32); A1 += __shfl_down(A1, 32);
    B0 += __shfl_down(B0, 32); B1 += __shfl_down(B1, 32);
    if (half == 0) {
        float2 bb = *(const float2*)(bias + 2 * f);
        float2 o;
        o.x = sigmoidf(A0 + bb.x);
        o.y = sigmoidf(A1 + bb.y);
        *(float2*)(outA + (size_t)row * 64 + 2 * f) = o;
        outB[(size_t)row * 32 + f] = pack_bf2(B0, B1);
    }
}

// ---------------------------------------------------------------------------
// Solo SpMM F=64 (paired-edge, R8-verbatim). ACT: 0 none (bf16), 3 sigmoid.
// ---------------------------------------------------------------------------
template<int ACT>
__launch_bounds__(256)
__global__ void spmm64_pair(const int* __restrict__ rowptr, const int2* __restrict__ edges,
                            const unsigned* __restrict__ src,    // [N][32] uint
                            void* __restrict__ out, int n)
{
    const int row = blockIdx.x * 4 + (threadIdx.x >> 6);
    const int lane = threadIdx.x & 63;
    const int f = lane & 31;
    const int half = lane >> 5;
    if (row >= n) return;
    const int s = rowptr[row];
    const int e = rowptr[row + 1];

    float a[4][2];
#pragma unroll
    for (int j = 0; j < 4; ++j) { a[j][0] = 0.f; a[j][1] = 0.f; }

    int i = s;
    for (; i + 8 <= e; i += 8) {
        int2 ed[4]; unsigned u[4];
#pragma unroll
        for (int j = 0; j < 4; ++j) ed[j] = ld_nt_int2(&edges[i + 2 * j + half]);
#pragma unroll
        for (int j = 0; j < 4; ++j) u[j] = src[(size_t)ed[j].x * 32 + f];
#pragma unroll
        for (int j = 0; j < 4; ++j) {
            float w = __int_as_float(ed[j].y);
            a[j][0] = fmaf(w, bf_lo(u[j]), a[j][0]);
            a[j][1] = fmaf(w, bf_hi(u[j]), a[j][1]);
        }
    }
    for (; i + 2 <= e; i += 2) {
        int2 ed = ld_nt_int2(&edges[i + half]);
        float w = __int_as_float(ed.y);
        unsigned u = src[(size_t)ed.x * 32 + f];
        a[0][0] = fmaf(w, bf_lo(u), a[0][0]);
        a[0][1] = fmaf(w, bf_hi(u), a[0][1]);
    }
    if (i < e && half == 0) {
        int2 ed = ld_nt_int2(&edges[i]);
        float w = __int_as_float(ed.y);
        unsigned u = src[(size_t)ed.x * 32 + f];
        a[1][0] = fmaf(w, bf_lo(u), a[1][0]);
        a[1][1] = fmaf(w, bf_hi(u), a[1][1]);
    }
    float v0 = (a[0][0] + a[1][0]) + (a[2][0] + a[3][0]);
    float v1 = (a[0][1] + a[1][1]) + (a[2][1] + a[3][1]);
    v0 += __shfl_down(v0, 32);
    v1 += __shfl_down(v1, 32);
    if (half == 0) {
        if (ACT == 0) {
            ((unsigned*)out)[(size_t)row * 32 + f] = pack_bf2(v0, v1);
        } else {
            float2 o;
            o.x = sigmoidf(v0);
            o.y = sigmoidf(v1);
            *(float2*)((float*)out + (size_t)row * 64 + 2 * f) = o;
        }
    }
}

// ---------------------------------------------------------------------------
extern "C" void kernel_launch(void* const* d_in, const int* in_sizes, int n_in,
                              void* d_out, int out_size, void* d_ws, size_t ws_size,
                              hipStream_t stream)
{
    const float* x    = (const float*)d_in[0];
    const float* soft = (const float*)d_in[1];
    const float* ea   = (const float*)d_in[2];
    const float* w1   = (const float*)d_in[3];
    const float* b1   = (const float*)d_in[4];
    const float* w2   = (const float*)d_in[5];
    const float* b2   = (const float*)d_in[6];
    const int*   eidx = (const int*)d_in[7];

    const int N = in_sizes[0] / 128;
    const int E = in_sizes[2];
    const int* row  = eidx;
    const int* colv = eidx + E;
    const int NB = (N + 255) / 256;            // coarse buckets (<= 256)
    const int chunk = (E + NBLK - 1) / NBLK;

    uint8_t* ws = (uint8_t*)d_ws;
    size_t off = 0;
    auto alloc = [&](size_t bytes) -> void* {
        void* p = ws + off;
        off += WS_ALIGN(bytes);
        return p;
    };
    int*  bucket_count = (int*) alloc((size_t)NB * 4);
    int*  bucket_start = (int*) alloc(((size_t)NB + 1) * 4);
    int*  bases        = (int*) alloc((size_t)NBLK * NB * 4);
    int*  rowptr       = (int*) alloc(((size_t)N + 1) * 4);
    int2* bk           = (int2*)alloc((size_t)E * 8);
    int2* edges        = (int2*)alloc((size_t)E * 8 + 64);
    unsigned short* w1p     = (unsigned short*)alloc((size_t)128 * 128 * 2);
    unsigned short* w2p     = (unsigned short*)alloc((size_t)128 * 64 * 2);
    unsigned short* xw1b    = (unsigned short*)alloc((size_t)N * 128 * 2);
    unsigned short* hb      = (unsigned short*)alloc((size_t)N * 128 * 2);
    unsigned short* logitsb = (unsigned short*)alloc((size_t)N * 64 * 2);
    unsigned short* softb   = (unsigned short*)alloc((size_t)N * 64 * 2);
    unsigned short* labA    = (unsigned short*)alloc((size_t)N * 64 * 2);
    unsigned short* labB    = (unsigned short*)alloc((size_t)N * 64 * 2);

    float* out0 = (float*)d_out;             // x_out [N,64]
    float* out1 = out0 + (size_t)N * 64;     // labels [N,64]

    hipMemsetAsync(bucket_count, 0, (size_t)NB * 4, stream);

    const int ns2 = (N * 64) / 2;
    const int gGemm = (N + 63) / 64;
    const int gSp   = (N + 3) / 4;

    // MERGED: binA_count || prep (w-pack, soft->bf16) — all independent.
    const int gCP = NBLK + 12 + (ns2 + 255) / 256;
    count_prep<<<gCP, 256, 0, stream>>>(row, bucket_count, bases, E, chunk, NB,
                                        soft, softb, ns2, w1, w1p, w2, w2p);

    bin_scan<<<1, 256, 0, stream>>>(bucket_count, bucket_start, NB);

    // MERGED: gemm128 (xw1, independent of CSR) || binA_scatter.
    gemm_scatter<<<gGemm + NBLK, 256, 0, stream>>>(x, w1p, xw1b, N, gGemm,
                                                   row, colv, ea, bucket_start, bases,
                                                   bk, E, chunk, NB);

    binB<<<NB, 256, 0, stream>>>(bk, bucket_start, rowptr, edges, N);

    // fused pass 1: h = relu(spmm(xw1)+b1), lab1 = spmm(soft)
    fused1_pair<<<gSp, 256, 0, stream>>>(rowptr, edges, (const uint2*)xw1b,
                                         (const unsigned*)softb, b1,
                                         (uint2*)hb, (unsigned*)labA, N);

    gemm_mfma<64><<<gGemm, 256, 0, stream>>>(hb, w2p, logitsb, N);       // logits (bf16)

    // fused pass 2: out0 = sigmoid(spmm(logits)+b2), lab2 = spmm(lab1)
    fused2_pair<<<gSp, 256, 0, stream>>>(rowptr, edges, (const unsigned*)logitsb,
                                         (const unsigned*)labA, b2,
                                         out0, (unsigned*)labB, N);

    // LPA tail (dependent): lab3, lab4, out1
    spmm64_pair<0><<<gSp, 256, 0, stream>>>(rowptr, edges, (const unsigned*)labB, labA, N);
    spmm64_pair<0><<<gSp, 256, 0, stream>>>(rowptr, edges, (const unsigned*)labA, labB, N);
    spmm64_pair<3><<<gSp, 256, 0, stream>>>(rowptr, edges, (const unsigned*)labB, out1, N);
}